// Round 1
// baseline (234.623 us; speedup 1.0000x reference)
//
#include <hip/hip_runtime.h>
#include <hip/hip_bf16.h>

// BertSelfAttention B=4,S=1024,HID=1024,H=16,D=64,MAXP=1024 — Round 8.
// R7 post-mortem: attn occupancy capped by GRID (512 blocks x 4 waves = 2
// waves/SIMD), not LDS. masked_softmax has no max-subtraction -> r-loop is
// additive -> split r-range across wave pairs. R8: 8-wave blocks (waves 0-3:
// r[0,512), waves 4-7: r[512,1024), additive combine via LDS at end) -> 4
// waves/SIMD. Es LDS roundtrip replaced by v_permlane32_swap in-register
// relayout (score C-frag -> PV B-frag). Tb stride 132->130 (bank spread).
// exp->exp2 with log2e folded into Q scale (covers QK and Toeplitz terms).
// ws: Xs[0,8M) Wt[8M,14M) Db[14M,14.25M) Qf[15M) Kf[23M) Vt[31M)

#define EPSV 1e-8f

typedef short bfrag __attribute__((ext_vector_type(8)));   // 8 bf16
typedef float cfrag __attribute__((ext_vector_type(16)));  // C/D 32x32
typedef int v2i __attribute__((ext_vector_type(2)));

__device__ __forceinline__ short f2bf(float f) {
    __hip_bfloat16 h = __float2bfloat16(f);
    return *reinterpret_cast<short*>(&h);
}
__device__ __forceinline__ float bf2f(short s) {
    unsigned int u = ((unsigned int)(unsigned short)s) << 16;
    return __builtin_bit_cast(float, u);
}
__device__ __forceinline__ unsigned int pk2(short a, short b) {
    return (unsigned int)(unsigned short)a | ((unsigned int)(unsigned short)b << 16);
}

// ---------------------------------------------------------------------------
// prep: fused cvt/swizzle. grid.x = 3648, 256 thr.
//  [0,2048): hidden -> Xs frag-major [4096 m][1024 k]
//  [2048,3584): Wq/Wk/Wv [k][n] -> Wt frag-major [1024 n][1024 k] (transpose)
//  [3584,3648): dist -> Db bf16 row-major [2047][64]
__global__ __launch_bounds__(256) void prep(
    const float* __restrict__ hidden, const float* __restrict__ Wq,
    const float* __restrict__ Wk, const float* __restrict__ Wv,
    const float* __restrict__ dist,
    short* __restrict__ Xs, short* __restrict__ Wt, short* __restrict__ Db)
{
    __shared__ short Tl[32 * 72];
    const int bid = blockIdx.x, tid = threadIdx.x;

    if (bid < 2048) {                      // X: 128 m-tiles x 16 k-groups
        const int mt = bid >> 4, kg = bid & 15;
        const int m_l = tid >> 3, k8 = (tid & 7) * 8;
        const float* src = hidden + (size_t)(mt * 32 + m_l) * 1024 + kg * 64 + k8;
        float4 v0 = *(const float4*)src, v1 = *(const float4*)(src + 4);
        short o[8];
        o[0] = f2bf(v0.x); o[1] = f2bf(v0.y); o[2] = f2bf(v0.z); o[3] = f2bf(v0.w);
        o[4] = f2bf(v1.x); o[5] = f2bf(v1.y); o[6] = f2bf(v1.z); o[7] = f2bf(v1.w);
        *(bfrag*)&Tl[m_l * 72 + k8] = *(bfrag*)o;
        __syncthreads();
        const int l31 = tid & 31, q2 = (tid >> 5) & 1, kc = tid >> 6;
        bfrag r = *(const bfrag*)&Tl[l31 * 72 + kc * 16 + q2 * 8];
        *(bfrag*)(Xs + ((size_t)(mt * 64 + kg * 4 + kc) * 64 + q2 * 32 + l31) * 8) = r;
    } else if (bid < 3584) {               // W: 3 z x 32 n-tiles x 16 k-groups
        const int t = bid - 2048, z = t >> 9, nt = (t >> 4) & 31, kg = t & 15;
        const float* W = (z == 0) ? Wq : ((z == 1) ? Wk : Wv);
        const int k_l = tid >> 2, n8 = (tid & 3) * 8;
        const float* src = W + (size_t)(kg * 64 + k_l) * 1024 + nt * 32 + n8;
        float4 v0 = *(const float4*)src, v1 = *(const float4*)(src + 4);
        float vv[8] = {v0.x, v0.y, v0.z, v0.w, v1.x, v1.y, v1.z, v1.w};
#pragma unroll
        for (int i = 0; i < 8; i++)
            Tl[(n8 + i) * 72 + k_l] = f2bf(vv[i]);   // transpose into LDS
        __syncthreads();
        const int l31 = tid & 31, q2 = (tid >> 5) & 1, kc = tid >> 6;
        bfrag r = *(const bfrag*)&Tl[l31 * 72 + kc * 16 + q2 * 8];
        *(bfrag*)(Wt + (size_t)z * 1048576
                  + ((size_t)(nt * 64 + kg * 4 + kc) * 64 + q2 * 32 + l31) * 8) = r;
    } else {                               // dist: 2047*64 = 131008 elems
        const int idx = (bid - 3584) * 256 + tid;
        if (idx < 16376) {
            const float* src = dist + (size_t)idx * 8;
            float4 v0 = *(const float4*)src, v1 = *(const float4*)(src + 4);
            short o[8];
            o[0] = f2bf(v0.x); o[1] = f2bf(v0.y); o[2] = f2bf(v0.z); o[3] = f2bf(v0.w);
            o[4] = f2bf(v1.x); o[5] = f2bf(v1.y); o[6] = f2bf(v1.z); o[7] = f2bf(v1.w);
            *(bfrag*)(Db + (size_t)idx * 8) = *(bfrag*)o;
        }
    }
}

// ---------------------------------------------------------------------------
// QKV GEMM, LDS-free: Xs/Wt frag-major in, Qf/Kf frag-major [s][d] per bh,
// Vt frag-major over V^T [d][s] per bh. 128x128 block, 4 waves 2x2 of 64x64.
__global__ __launch_bounds__(256) void qkv_mfma(
    const short* __restrict__ Xs, const short* __restrict__ Wt,
    const float* __restrict__ bq, const float* __restrict__ bk,
    const float* __restrict__ bv,
    short* __restrict__ Qf, short* __restrict__ Kf, short* __restrict__ Vt)
{
    const int z = blockIdx.z;
    const short* W = Wt + (size_t)z * 1048576;
    const float* bias = (z == 0) ? bq : ((z == 1) ? bk : bv);
    // fold 1/sqrt(D) AND log2(e) into Q: 0.125 * 1.4426950408889634
    const float scale = (z == 0) ? 0.18033688011112042f : 1.0f;

    const int tid = threadIdx.x, lane = tid & 63, wid = tid >> 6;
    const int q2 = lane >> 5, l31 = lane & 31;
    const int wr = wid >> 1, wc = wid & 1;
    const int m0 = blockIdx.x * 128, n0 = blockIdx.y * 128;

    cfrag acc[2][2];
#pragma unroll
    for (int i = 0; i < 2; i++)
#pragma unroll
        for (int j = 0; j < 2; j++)
#pragma unroll
            for (int e = 0; e < 16; e++) acc[i][j][e] = 0.f;

    const short* ap0 = Xs + ((size_t)((m0 >> 5) + wr * 2 + 0) * 64 * 64 + lane) * 8;
    const short* ap1 = Xs + ((size_t)((m0 >> 5) + wr * 2 + 1) * 64 * 64 + lane) * 8;
    const short* bp0 = W  + ((size_t)((n0 >> 5) + wc * 2 + 0) * 64 * 64 + lane) * 8;
    const short* bp1 = W  + ((size_t)((n0 >> 5) + wc * 2 + 1) * 64 * 64 + lane) * 8;

#pragma unroll 4
    for (int kc = 0; kc < 64; kc++) {
        const int off = kc * 512;          // 64 chunks * 8 shorts
        bfrag a0 = *(const bfrag*)(ap0 + off);
        bfrag a1 = *(const bfrag*)(ap1 + off);
        bfrag b0 = *(const bfrag*)(bp0 + off);
        bfrag b1 = *(const bfrag*)(bp1 + off);
        acc[0][0] = __builtin_amdgcn_mfma_f32_32x32x16_bf16(a0, b0, acc[0][0], 0, 0, 0);
        acc[0][1] = __builtin_amdgcn_mfma_f32_32x32x16_bf16(a0, b1, acc[0][1], 0, 0, 0);
        acc[1][0] = __builtin_amdgcn_mfma_f32_32x32x16_bf16(a1, b0, acc[1][0], 0, 0, 0);
        acc[1][1] = __builtin_amdgcn_mfma_f32_32x32x16_bf16(a1, b1, acc[1][1], 0, 0, 0);
    }

    // epilogue: +bias, (Q: x scale), cvt bf16, scatter frag-major per bh
#pragma unroll
    for (int nt = 0; nt < 2; nt++) {
        const int c = n0 + wc * 64 + nt * 32 + l31;    // channel
        const float bval = bias[c];
        const int h = c >> 6;
        const int d = nt * 32 + l31;                   // c & 63
#pragma unroll
        for (int mt = 0; mt < 2; mt++) {
            const int tok0 = m0 + wr * 64 + mt * 32;
            const int bb = tok0 >> 10, s_base = tok0 & 1023;
            const size_t bhbase = (size_t)(bb * 16 + h) * 65536;
            if (z < 2) {
                short* outp = (z == 0) ? Qf : Kf;
                const size_t fbase = bhbase
                    + ((size_t)((s_base >> 5) * 4 + (d >> 4)) * 64
                       + ((d >> 3) & 1) * 32) * 8 + (d & 7);
#pragma unroll
                for (int reg = 0; reg < 16; reg++) {
                    const int row = (reg & 3) + 8 * (reg >> 2) + 4 * q2;
                    outp[fbase + (size_t)row * 8] = f2bf((acc[mt][nt][reg] + bval) * scale);
                }
            } else {
                // V^T frag-major: elem (d, s): ((d>>5)*64 + (s>>4))*64*8 ...
#pragma unroll
                for (int g = 0; g < 4; g++) {
                    const float e0 = acc[mt][nt][4 * g + 0] + bval;
                    const float e1 = acc[mt][nt][4 * g + 1] + bval;
                    const float e2 = acc[mt][nt][4 * g + 2] + bval;
                    const float e3 = acc[mt][nt][4 * g + 3] + bval;
                    uint2 w2;
                    w2.x = pk2(f2bf(e0), f2bf(e1));
                    w2.y = pk2(f2bf(e2), f2bf(e3));
                    const size_t flat = bhbase
                        + ((size_t)(nt * 64 + (s_base >> 4) + (g >> 1)) * 64
                           + (g & 1) * 32 + l31) * 8 + 4 * q2;
                    *(uint2*)(Vt + flat) = w2;
                }
            }
        }
    }
}

// ---------------------------------------------------------------------------
// Fused attention. grid (64 bh = x, 8 l-tiles = y), 512 thr (8 waves).
// Wave w: l-cols [l0 + 32*(w&3), +32), r-half (w>>2) of [0,1024).
// masked_softmax has no max-subtraction -> r-split partials combine by ADD.
// Barrier-free main loop (Tb rows wave-private); end: additive combine via LDS.
__global__ __launch_bounds__(512, 4) void attn_mfma(
    const short* __restrict__ Qf, const short* __restrict__ Kf,
    const short* __restrict__ Vt, const short* __restrict__ Db,
    const float* __restrict__ amask, const int* __restrict__ skim,
    float* __restrict__ out)
{
    __shared__ short Tb[256 * 130];   // rolling T[lane-row][slot], stride 130
    __shared__ float Lg[1024];        // g[r] = exp(amask)*skim

    const int tid = threadIdx.x, lane = tid & 63, w = tid >> 6;
    const int q2 = lane >> 5, l31 = lane & 31;
    const int wl = w & 3, rh = w >> 2;
    const int h2 = wl >> 1;
    const int bh = blockIdx.x, b = bh >> 4, hh = bh & 15;
    const int l0 = blockIdx.y * 128;

    {
        const int r2 = tid * 2;
        float2 am = *(const float2*)(amask + b * 1024 + r2);
        int2 sk = *(const int2*)(skim + b * 1024 + r2);
        Lg[r2 + 0] = __expf(am.x) * (float)sk.x;
        Lg[r2 + 1] = __expf(am.y) * (float)sk.y;
    }
    __syncthreads();

    const short* Qg = Qf + (size_t)bh * 65536;
    const short* Kg = Kf + (size_t)bh * 65536;
    const short* Vg = Vt + (size_t)bh * 65536;

    // Q B-frags (pre-scaled by log2e/8): chunk (((l0>>5)+wl)*4 + c)*64 + lane
    bfrag qa[4];
#pragma unroll
    for (int c = 0; c < 4; c++)
        qa[c] = *(const bfrag*)(Qg + ((size_t)(((l0 >> 5) + wl) * 4 + c) * 64 + lane) * 8);

    cfrag oacc[2];
#pragma unroll
    for (int mt = 0; mt < 2; mt++)
#pragma unroll
        for (int e = 0; e < 16; e++) oacc[mt][e] = 0.f;
    float es[4] = {0.f, 0.f, 0.f, 0.f};

    const int lrow130 = (32 * w + l31) * 130;
    const int lg = l0 + 32 * wl + l31;
    const int rbase = rh * 512;

    for (int r0 = rbase - 64; r0 < rbase + 512; r0 += 64) {
        // ---- Toeplitz T^T: new 64-dist block for this wave's l-half ----
        const int bd = l0 - r0 - 64 + 64 * h2;
#pragma unroll
        for (int mt = 0; mt < 2; mt++) {
            cfrag t;
#pragma unroll
            for (int e = 0; e < 16; e++) t[e] = 0.f;
            const int drow = bd + 32 * mt + l31;
            const int er = min(max(drow + 1023, 0), 2046);
#pragma unroll
            for (int kc = 0; kc < 4; kc++) {
                bfrag pb = *(const bfrag*)(Db + (size_t)er * 64 + kc * 16 + q2 * 8);
                t = __builtin_amdgcn_mfma_f32_32x32x16_bf16(pb, qa[kc], t, 0, 0, 0);
            }
#pragma unroll
            for (int g = 0; g < 4; g++) {
                const int slot = (bd + 32 * mt + 8 * g + 4 * q2) & 127;
                *(unsigned int*)&Tb[lrow130 + slot] =
                    pk2(f2bf(t[4 * g + 0]), f2bf(t[4 * g + 1]));
                *(unsigned int*)&Tb[lrow130 + slot + 2] =
                    pk2(f2bf(t[4 * g + 2]), f2bf(t[4 * g + 3]));
            }
        }
        if (r0 < rbase) continue;

        // ---- scores S^T = K . Q^T, K A-frags coalesced ----
        cfrag sfr[2];
#pragma unroll
        for (int mt = 0; mt < 2; mt++) {
#pragma unroll
            for (int e = 0; e < 16; e++) sfr[mt][e] = 0.f;
#pragma unroll
            for (int kc = 0; kc < 4; kc++) {
                bfrag kb = *(const bfrag*)(Kg
                    + ((size_t)(((r0 >> 5) + mt) * 4 + kc) * 64 + lane) * 8);
                sfr[mt] = __builtin_amdgcn_mfma_f32_32x32x16_bf16(
                    kb, qa[kc], sfr[mt], 0, 0, 0);
            }
        }

        // ---- masked-softmax numerators, in-register relayout, PV ----
#pragma unroll
        for (int mt = 0; mt < 2; mt++) {
            unsigned int P[4][2];
#pragma unroll
            for (int g = 0; g < 4; g++) {
                const int rb = r0 + 32 * mt + 8 * g + 4 * q2;
                float4 g4 = *(const float4*)&Lg[rb];
                float ev[4];
#pragma unroll
                for (int j = 0; j < 4; j++) {
                    const int dist = lg - (rb + j);
                    const float tv = bf2f(Tb[lrow130 + (dist & 127)]);
                    const float gv = (j == 0) ? g4.x : (j == 1) ? g4.y
                                   : (j == 2) ? g4.z : g4.w;
                    ev[j] = __builtin_amdgcn_exp2f(sfr[mt][4 * g + j] + tv) * gv;
                    es[j] += ev[j];
                }
                P[g][0] = pk2(f2bf(ev[0]), f2bf(ev[1]));
                P[g][1] = pk2(f2bf(ev[2]), f2bf(ev[3]));
            }
            // chunk c (16 r): B-frag dwords {0,2} = swap(x0,y0), {1,3} = swap(x1,y1)
#pragma unroll
            for (int c = 0; c < 2; c++) {
                v2i s0 = __builtin_amdgcn_permlane32_swap(
                    (int)P[2 * c][0], (int)P[2 * c + 1][0], false, false);
                v2i s1 = __builtin_amdgcn_permlane32_swap(
                    (int)P[2 * c][1], (int)P[2 * c + 1][1], false, false);
                union { bfrag f; int d[4]; } u;
                u.d[0] = s0[0]; u.d[1] = s1[0]; u.d[2] = s0[1]; u.d[3] = s1[1];
                const int kc = 2 * mt + c;
#pragma unroll
                for (int mtd = 0; mtd < 2; mtd++) {
                    bfrag vb = *(const bfrag*)(Vg
                        + ((size_t)(mtd * 64 + (r0 >> 4) + kc) * 64 + lane) * 8);
                    oacc[mtd] = __builtin_amdgcn_mfma_f32_32x32x16_bf16(
                        vb, u.f, oacc[mtd], 0, 0, 0);
                }
            }
        }
    }

    float esum = (es[0] + es[1]) + (es[2] + es[3]);

    // ---- combine r-halves (pure addition, no rescale) ----
    __syncthreads();                      // all waves done reading Tb
    float* Sb = (float*)Tb;               // reuse Tb: 8448 floats = 33.8 KB
    if (rh == 1) {
#pragma unroll
        for (int mtd = 0; mtd < 2; mtd++)
#pragma unroll
            for (int e = 0; e < 16; e++)
                Sb[((mtd * 16 + e) * 4 + wl) * 64 + lane] = oacc[mtd][e];
        Sb[8192 + wl * 64 + lane] = esum;
    }
    __syncthreads();
    if (rh == 0) {
#pragma unroll
        for (int mtd = 0; mtd < 2; mtd++)
#pragma unroll
            for (int e = 0; e < 16; e++)
                oacc[mtd][e] += Sb[((mtd * 16 + e) * 4 + wl) * 64 + lane];
        esum += Sb[8192 + wl * 64 + lane];

        const float den = EPSV + esum + __shfl_xor(esum, 32);
        const float inv = 1.0f / den;
        float* ob = out + ((size_t)(b * 1024 + lg) * 1024) + hh * 64;
#pragma unroll
        for (int mtd = 0; mtd < 2; mtd++) {
#pragma unroll
            for (int g = 0; g < 4; g++) {
                float4 o;
                o.x = oacc[mtd][4 * g + 0] * inv;
                o.y = oacc[mtd][4 * g + 1] * inv;
                o.z = oacc[mtd][4 * g + 2] * inv;
                o.w = oacc[mtd][4 * g + 3] * inv;
                *(float4*)(ob + 32 * mtd + 8 * g + 4 * q2) = o;
            }
        }
    }
}

// ---------------------------------------------------------------------------
extern "C" void kernel_launch(void* const* d_in, const int* in_sizes, int n_in,
                              void* d_out, int out_size, void* d_ws, size_t ws_size,
                              hipStream_t stream) {
    const float* hidden = (const float*)d_in[0];
    const float* amask  = (const float*)d_in[1];
    const int*   skim   = (const int*)d_in[2];
    const float* Wq     = (const float*)d_in[3];
    const float* bq     = (const float*)d_in[4];
    const float* Wk     = (const float*)d_in[5];
    const float* bk     = (const float*)d_in[6];
    const float* Wv     = (const float*)d_in[7];
    const float* bv     = (const float*)d_in[8];
    const float* dist   = (const float*)d_in[9];
    float* out = (float*)d_out;

    char* w = (char*)d_ws;
    short* Xs  = (short*)(w);                        // 8 MB frag-major X
    short* Wt  = (short*)(w + ((size_t)8 << 20));    // 6 MB frag-major W^T
    short* Db  = (short*)(w + ((size_t)14 << 20));   // 0.25 MB dist bf16
    short* Qf  = (short*)(w + ((size_t)15 << 20));   // 8 MB frag-major Q
    short* Kf  = (short*)(w + ((size_t)23 << 20));   // 8 MB frag-major K
    short* Vt  = (short*)(w + ((size_t)31 << 20));   // 8 MB frag-major V^T

    prep<<<3648, 256, 0, stream>>>(hidden, Wq, Wk, Wv, dist, Xs, Wt, Db);
    qkv_mfma<<<dim3(32, 8, 3), 256, 0, stream>>>(Xs, Wt, bq, bk, bv, Qf, Kf, Vt);
    attn_mfma<<<dim3(64, 8), 512, 0, stream>>>(Qf, Kf, Vt, Db, amask, skim, out);
}

// Round 3
// 206.965 us; speedup vs baseline: 1.1336x; 1.1336x over previous
//
#include <hip/hip_runtime.h>
#include <hip/hip_bf16.h>

// BertSelfAttention B=4,S=1024,HID=1024,H=16,D=64,MAXP=1024 — Round 10
// (= R9 resubmitted; R9 bench was an infra failure, container died twice,
// no counters returned).
// R8 post-mortem: __launch_bounds__(512,4) acted as 4 blocks/CU -> VGPR
// forced to 64 (8 waves/EU budget) -> ~45 regs spilled -> 195 MB/dispatch
// scratch traffic (WRITE 159MB vs 16MB output), dur 71->108us. The 8-wave
// additive r-split itself worked (occupancy 17.8->41%).
// R9/R10: __launch_bounds__(512,2) (VGPR cap 128 = 2 blocks/CU budget) +
// compute score frag per-mt (one 16-reg sfr live instead of two) -> peak
// ~100 VGPR, no spill, keep 4 waves/SIMD.
// ws: Xs[0,8M) Wt[8M,14M) Db[14M,14.25M) Qf[15M) Kf[23M) Vt[31M)

#define EPSV 1e-8f

typedef short bfrag __attribute__((ext_vector_type(8)));   // 8 bf16
typedef float cfrag __attribute__((ext_vector_type(16)));  // C/D 32x32
typedef int v2i __attribute__((ext_vector_type(2)));

__device__ __forceinline__ short f2bf(float f) {
    __hip_bfloat16 h = __float2bfloat16(f);
    return *reinterpret_cast<short*>(&h);
}
__device__ __forceinline__ float bf2f(short s) {
    unsigned int u = ((unsigned int)(unsigned short)s) << 16;
    return __builtin_bit_cast(float, u);
}
__device__ __forceinline__ unsigned int pk2(short a, short b) {
    return (unsigned int)(unsigned short)a | ((unsigned int)(unsigned short)b << 16);
}

// ---------------------------------------------------------------------------
// prep: fused cvt/swizzle. grid.x = 3648, 256 thr.
//  [0,2048): hidden -> Xs frag-major [4096 m][1024 k]
//  [2048,3584): Wq/Wk/Wv [k][n] -> Wt frag-major [1024 n][1024 k] (transpose)
//  [3584,3648): dist -> Db bf16 row-major [2047][64]
__global__ __launch_bounds__(256) void prep(
    const float* __restrict__ hidden, const float* __restrict__ Wq,
    const float* __restrict__ Wk, const float* __restrict__ Wv,
    const float* __restrict__ dist,
    short* __restrict__ Xs, short* __restrict__ Wt, short* __restrict__ Db)
{
    __shared__ short Tl[32 * 72];
    const int bid = blockIdx.x, tid = threadIdx.x;

    if (bid < 2048) {                      // X: 128 m-tiles x 16 k-groups
        const int mt = bid >> 4, kg = bid & 15;
        const int m_l = tid >> 3, k8 = (tid & 7) * 8;
        const float* src = hidden + (size_t)(mt * 32 + m_l) * 1024 + kg * 64 + k8;
        float4 v0 = *(const float4*)src, v1 = *(const float4*)(src + 4);
        short o[8];
        o[0] = f2bf(v0.x); o[1] = f2bf(v0.y); o[2] = f2bf(v0.z); o[3] = f2bf(v0.w);
        o[4] = f2bf(v1.x); o[5] = f2bf(v1.y); o[6] = f2bf(v1.z); o[7] = f2bf(v1.w);
        *(bfrag*)&Tl[m_l * 72 + k8] = *(bfrag*)o;
        __syncthreads();
        const int l31 = tid & 31, q2 = (tid >> 5) & 1, kc = tid >> 6;
        bfrag r = *(const bfrag*)&Tl[l31 * 72 + kc * 16 + q2 * 8];
        *(bfrag*)(Xs + ((size_t)(mt * 64 + kg * 4 + kc) * 64 + q2 * 32 + l31) * 8) = r;
    } else if (bid < 3584) {               // W: 3 z x 32 n-tiles x 16 k-groups
        const int t = bid - 2048, z = t >> 9, nt = (t >> 4) & 31, kg = t & 15;
        const float* W = (z == 0) ? Wq : ((z == 1) ? Wk : Wv);
        const int k_l = tid >> 2, n8 = (tid & 3) * 8;
        const float* src = W + (size_t)(kg * 64 + k_l) * 1024 + nt * 32 + n8;
        float4 v0 = *(const float4*)src, v1 = *(const float4*)(src + 4);
        float vv[8] = {v0.x, v0.y, v0.z, v0.w, v1.x, v1.y, v1.z, v1.w};
#pragma unroll
        for (int i = 0; i < 8; i++)
            Tl[(n8 + i) * 72 + k_l] = f2bf(vv[i]);   // transpose into LDS
        __syncthreads();
        const int l31 = tid & 31, q2 = (tid >> 5) & 1, kc = tid >> 6;
        bfrag r = *(const bfrag*)&Tl[l31 * 72 + kc * 16 + q2 * 8];
        *(bfrag*)(Wt + (size_t)z * 1048576
                  + ((size_t)(nt * 64 + kg * 4 + kc) * 64 + q2 * 32 + l31) * 8) = r;
    } else {                               // dist: 2047*64 = 131008 elems
        const int idx = (bid - 3584) * 256 + tid;
        if (idx < 16376) {
            const float* src = dist + (size_t)idx * 8;
            float4 v0 = *(const float4*)src, v1 = *(const float4*)(src + 4);
            short o[8];
            o[0] = f2bf(v0.x); o[1] = f2bf(v0.y); o[2] = f2bf(v0.z); o[3] = f2bf(v0.w);
            o[4] = f2bf(v1.x); o[5] = f2bf(v1.y); o[6] = f2bf(v1.z); o[7] = f2bf(v1.w);
            *(bfrag*)(Db + (size_t)idx * 8) = *(bfrag*)o;
        }
    }
}

// ---------------------------------------------------------------------------
// QKV GEMM, LDS-free: Xs/Wt frag-major in, Qf/Kf frag-major [s][d] per bh,
// Vt frag-major over V^T [d][s] per bh. 128x128 block, 4 waves 2x2 of 64x64.
__global__ __launch_bounds__(256) void qkv_mfma(
    const short* __restrict__ Xs, const short* __restrict__ Wt,
    const float* __restrict__ bq, const float* __restrict__ bk,
    const float* __restrict__ bv,
    short* __restrict__ Qf, short* __restrict__ Kf, short* __restrict__ Vt)
{
    const int z = blockIdx.z;
    const short* W = Wt + (size_t)z * 1048576;
    const float* bias = (z == 0) ? bq : ((z == 1) ? bk : bv);
    // fold 1/sqrt(D) AND log2(e) into Q: 0.125 * 1.4426950408889634
    const float scale = (z == 0) ? 0.18033688011112042f : 1.0f;

    const int tid = threadIdx.x, lane = tid & 63, wid = tid >> 6;
    const int q2 = lane >> 5, l31 = lane & 31;
    const int wr = wid >> 1, wc = wid & 1;
    const int m0 = blockIdx.x * 128, n0 = blockIdx.y * 128;

    cfrag acc[2][2];
#pragma unroll
    for (int i = 0; i < 2; i++)
#pragma unroll
        for (int j = 0; j < 2; j++)
#pragma unroll
            for (int e = 0; e < 16; e++) acc[i][j][e] = 0.f;

    const short* ap0 = Xs + ((size_t)((m0 >> 5) + wr * 2 + 0) * 64 * 64 + lane) * 8;
    const short* ap1 = Xs + ((size_t)((m0 >> 5) + wr * 2 + 1) * 64 * 64 + lane) * 8;
    const short* bp0 = W  + ((size_t)((n0 >> 5) + wc * 2 + 0) * 64 * 64 + lane) * 8;
    const short* bp1 = W  + ((size_t)((n0 >> 5) + wc * 2 + 1) * 64 * 64 + lane) * 8;

#pragma unroll 4
    for (int kc = 0; kc < 64; kc++) {
        const int off = kc * 512;          // 64 chunks * 8 shorts
        bfrag a0 = *(const bfrag*)(ap0 + off);
        bfrag a1 = *(const bfrag*)(ap1 + off);
        bfrag b0 = *(const bfrag*)(bp0 + off);
        bfrag b1 = *(const bfrag*)(bp1 + off);
        acc[0][0] = __builtin_amdgcn_mfma_f32_32x32x16_bf16(a0, b0, acc[0][0], 0, 0, 0);
        acc[0][1] = __builtin_amdgcn_mfma_f32_32x32x16_bf16(a0, b1, acc[0][1], 0, 0, 0);
        acc[1][0] = __builtin_amdgcn_mfma_f32_32x32x16_bf16(a1, b0, acc[1][0], 0, 0, 0);
        acc[1][1] = __builtin_amdgcn_mfma_f32_32x32x16_bf16(a1, b1, acc[1][1], 0, 0, 0);
    }

    // epilogue: +bias, (Q: x scale), cvt bf16, scatter frag-major per bh
#pragma unroll
    for (int nt = 0; nt < 2; nt++) {
        const int c = n0 + wc * 64 + nt * 32 + l31;    // channel
        const float bval = bias[c];
        const int h = c >> 6;
        const int d = nt * 32 + l31;                   // c & 63
#pragma unroll
        for (int mt = 0; mt < 2; mt++) {
            const int tok0 = m0 + wr * 64 + mt * 32;
            const int bb = tok0 >> 10, s_base = tok0 & 1023;
            const size_t bhbase = (size_t)(bb * 16 + h) * 65536;
            if (z < 2) {
                short* outp = (z == 0) ? Qf : Kf;
                const size_t fbase = bhbase
                    + ((size_t)((s_base >> 5) * 4 + (d >> 4)) * 64
                       + ((d >> 3) & 1) * 32) * 8 + (d & 7);
#pragma unroll
                for (int reg = 0; reg < 16; reg++) {
                    const int row = (reg & 3) + 8 * (reg >> 2) + 4 * q2;
                    outp[fbase + (size_t)row * 8] = f2bf((acc[mt][nt][reg] + bval) * scale);
                }
            } else {
                // V^T frag-major: elem (d, s): ((d>>5)*64 + (s>>4))*64*8 ...
#pragma unroll
                for (int g = 0; g < 4; g++) {
                    const float e0 = acc[mt][nt][4 * g + 0] + bval;
                    const float e1 = acc[mt][nt][4 * g + 1] + bval;
                    const float e2 = acc[mt][nt][4 * g + 2] + bval;
                    const float e3 = acc[mt][nt][4 * g + 3] + bval;
                    uint2 w2;
                    w2.x = pk2(f2bf(e0), f2bf(e1));
                    w2.y = pk2(f2bf(e2), f2bf(e3));
                    const size_t flat = bhbase
                        + ((size_t)(nt * 64 + (s_base >> 4) + (g >> 1)) * 64
                           + (g & 1) * 32 + l31) * 8 + 4 * q2;
                    *(uint2*)(Vt + flat) = w2;
                }
            }
        }
    }
}

// ---------------------------------------------------------------------------
// Fused attention. grid (64 bh = x, 8 l-tiles = y), 512 thr (8 waves).
// Wave w: l-cols [l0 + 32*(w&3), +32), r-half (w>>2) of [0,1024).
// masked_softmax has no max-subtraction -> r-split partials combine by ADD.
// Barrier-free main loop (Tb rows wave-private); end: additive combine via LDS.
// launch_bounds (512,2): VGPR cap 128 (2 blocks/CU budget) — (512,4) forced
// VGPR=64 and spilled ~195MB/dispatch to scratch (R8).
__global__ __launch_bounds__(512, 2) void attn_mfma(
    const short* __restrict__ Qf, const short* __restrict__ Kf,
    const short* __restrict__ Vt, const short* __restrict__ Db,
    const float* __restrict__ amask, const int* __restrict__ skim,
    float* __restrict__ out)
{
    __shared__ short Tb[256 * 130];   // rolling T[lane-row][slot], stride 130
    __shared__ float Lg[1024];        // g[r] = exp(amask)*skim

    const int tid = threadIdx.x, lane = tid & 63, w = tid >> 6;
    const int q2 = lane >> 5, l31 = lane & 31;
    const int wl = w & 3, rh = w >> 2;
    const int h2 = wl >> 1;
    const int bh = blockIdx.x, b = bh >> 4, hh = bh & 15;
    const int l0 = blockIdx.y * 128;

    {
        const int r2 = tid * 2;
        float2 am = *(const float2*)(amask + b * 1024 + r2);
        int2 sk = *(const int2*)(skim + b * 1024 + r2);
        Lg[r2 + 0] = __expf(am.x) * (float)sk.x;
        Lg[r2 + 1] = __expf(am.y) * (float)sk.y;
    }
    __syncthreads();

    const short* Qg = Qf + (size_t)bh * 65536;
    const short* Kg = Kf + (size_t)bh * 65536;
    const short* Vg = Vt + (size_t)bh * 65536;

    // Q B-frags (pre-scaled by log2e/8): chunk (((l0>>5)+wl)*4 + c)*64 + lane
    bfrag qa[4];
#pragma unroll
    for (int c = 0; c < 4; c++)
        qa[c] = *(const bfrag*)(Qg + ((size_t)(((l0 >> 5) + wl) * 4 + c) * 64 + lane) * 8);

    cfrag oacc[2];
#pragma unroll
    for (int mt = 0; mt < 2; mt++)
#pragma unroll
        for (int e = 0; e < 16; e++) oacc[mt][e] = 0.f;
    float es[4] = {0.f, 0.f, 0.f, 0.f};

    const int lrow130 = (32 * w + l31) * 130;
    const int lg = l0 + 32 * wl + l31;
    const int rbase = rh * 512;

    for (int r0 = rbase - 64; r0 < rbase + 512; r0 += 64) {
        // ---- Toeplitz T^T: new 64-dist block for this wave's l-half ----
        const int bd = l0 - r0 - 64 + 64 * h2;
#pragma unroll
        for (int mt = 0; mt < 2; mt++) {
            cfrag t;
#pragma unroll
            for (int e = 0; e < 16; e++) t[e] = 0.f;
            const int drow = bd + 32 * mt + l31;
            const int er = min(max(drow + 1023, 0), 2046);
#pragma unroll
            for (int kc = 0; kc < 4; kc++) {
                bfrag pb = *(const bfrag*)(Db + (size_t)er * 64 + kc * 16 + q2 * 8);
                t = __builtin_amdgcn_mfma_f32_32x32x16_bf16(pb, qa[kc], t, 0, 0, 0);
            }
#pragma unroll
            for (int g = 0; g < 4; g++) {
                const int slot = (bd + 32 * mt + 8 * g + 4 * q2) & 127;
                *(unsigned int*)&Tb[lrow130 + slot] =
                    pk2(f2bf(t[4 * g + 0]), f2bf(t[4 * g + 1]));
                *(unsigned int*)&Tb[lrow130 + slot + 2] =
                    pk2(f2bf(t[4 * g + 2]), f2bf(t[4 * g + 3]));
            }
        }
        if (r0 < rbase) continue;

        // ---- per 32-r block: scores, masked-softmax, relayout, PV ----
#pragma unroll
        for (int mt = 0; mt < 2; mt++) {
            // scores S^T = K . Q^T, K A-frags coalesced (one sfr live)
            cfrag sfr;
#pragma unroll
            for (int e = 0; e < 16; e++) sfr[e] = 0.f;
#pragma unroll
            for (int kc = 0; kc < 4; kc++) {
                bfrag kb = *(const bfrag*)(Kg
                    + ((size_t)(((r0 >> 5) + mt) * 4 + kc) * 64 + lane) * 8);
                sfr = __builtin_amdgcn_mfma_f32_32x32x16_bf16(kb, qa[kc], sfr, 0, 0, 0);
            }

            // masked-softmax numerators -> packed bf16 pairs
            unsigned int P[4][2];
#pragma unroll
            for (int g = 0; g < 4; g++) {
                const int rb = r0 + 32 * mt + 8 * g + 4 * q2;
                float4 g4 = *(const float4*)&Lg[rb];
                float ev[4];
#pragma unroll
                for (int j = 0; j < 4; j++) {
                    const int dist = lg - (rb + j);
                    const float tv = bf2f(Tb[lrow130 + (dist & 127)]);
                    const float gv = (j == 0) ? g4.x : (j == 1) ? g4.y
                                   : (j == 2) ? g4.z : g4.w;
                    ev[j] = __builtin_amdgcn_exp2f(sfr[4 * g + j] + tv) * gv;
                    es[j] += ev[j];
                }
                P[g][0] = pk2(f2bf(ev[0]), f2bf(ev[1]));
                P[g][1] = pk2(f2bf(ev[2]), f2bf(ev[3]));
            }
            // chunk c (16 r): B-frag dwords {0,2} = swap(x0,y0), {1,3} = swap(x1,y1)
#pragma unroll
            for (int c = 0; c < 2; c++) {
                v2i s0 = __builtin_amdgcn_permlane32_swap(
                    (int)P[2 * c][0], (int)P[2 * c + 1][0], false, false);
                v2i s1 = __builtin_amdgcn_permlane32_swap(
                    (int)P[2 * c][1], (int)P[2 * c + 1][1], false, false);
                union { bfrag f; int d[4]; } u;
                u.d[0] = s0[0]; u.d[1] = s1[0]; u.d[2] = s0[1]; u.d[3] = s1[1];
                const int kc = 2 * mt + c;
#pragma unroll
                for (int mtd = 0; mtd < 2; mtd++) {
                    bfrag vb = *(const bfrag*)(Vg
                        + ((size_t)(mtd * 64 + (r0 >> 4) + kc) * 64 + lane) * 8);
                    oacc[mtd] = __builtin_amdgcn_mfma_f32_32x32x16_bf16(
                        vb, u.f, oacc[mtd], 0, 0, 0);
                }
            }
        }
    }

    float esum = (es[0] + es[1]) + (es[2] + es[3]);

    // ---- combine r-halves (pure addition, no rescale) ----
    __syncthreads();                      // all waves done reading Tb
    float* Sb = (float*)Tb;               // reuse Tb: 8448 floats = 33.8 KB
    if (rh == 1) {
#pragma unroll
        for (int mtd = 0; mtd < 2; mtd++)
#pragma unroll
            for (int e = 0; e < 16; e++)
                Sb[((mtd * 16 + e) * 4 + wl) * 64 + lane] = oacc[mtd][e];
        Sb[8192 + wl * 64 + lane] = esum;
    }
    __syncthreads();
    if (rh == 0) {
#pragma unroll
        for (int mtd = 0; mtd < 2; mtd++)
#pragma unroll
            for (int e = 0; e < 16; e++)
                oacc[mtd][e] += Sb[((mtd * 16 + e) * 4 + wl) * 64 + lane];
        esum += Sb[8192 + wl * 64 + lane];

        const float den = EPSV + esum + __shfl_xor(esum, 32);
        const float inv = 1.0f / den;
        float* ob = out + ((size_t)(b * 1024 + lg) * 1024) + hh * 64;
#pragma unroll
        for (int mtd = 0; mtd < 2; mtd++) {
#pragma unroll
            for (int g = 0; g < 4; g++) {
                float4 o;
                o.x = oacc[mtd][4 * g + 0] * inv;
                o.y = oacc[mtd][4 * g + 1] * inv;
                o.z = oacc[mtd][4 * g + 2] * inv;
                o.w = oacc[mtd][4 * g + 3] * inv;
                *(float4*)(ob + 32 * mtd + 8 * g + 4 * q2) = o;
            }
        }
    }
}

// ---------------------------------------------------------------------------
extern "C" void kernel_launch(void* const* d_in, const int* in_sizes, int n_in,
                              void* d_out, int out_size, void* d_ws, size_t ws_size,
                              hipStream_t stream) {
    const float* hidden = (const float*)d_in[0];
    const float* amask  = (const float*)d_in[1];
    const int*   skim   = (const int*)d_in[2];
    const float* Wq     = (const float*)d_in[3];
    const float* bq     = (const float*)d_in[4];
    const float* Wk     = (const float*)d_in[5];
    const float* bk     = (const float*)d_in[6];
    const float* Wv     = (const float*)d_in[7];
    const float* bv     = (const float*)d_in[8];
    const float* dist   = (const float*)d_in[9];
    float* out = (float*)d_out;

    char* w = (char*)d_ws;
    short* Xs  = (short*)(w);                        // 8 MB frag-major X
    short* Wt  = (short*)(w + ((size_t)8 << 20));    // 6 MB frag-major W^T
    short* Db  = (short*)(w + ((size_t)14 << 20));   // 0.25 MB dist bf16
    short* Qf  = (short*)(w + ((size_t)15 << 20));   // 8 MB frag-major Q
    short* Kf  = (short*)(w + ((size_t)23 << 20));   // 8 MB frag-major K
    short* Vt  = (short*)(w + ((size_t)31 << 20));   // 8 MB frag-major V^T

    prep<<<3648, 256, 0, stream>>>(hidden, Wq, Wk, Wv, dist, Xs, Wt, Db);
    qkv_mfma<<<dim3(32, 8, 3), 256, 0, stream>>>(Xs, Wt, bq, bk, bv, Qf, Kf, Vt);
    attn_mfma<<<dim3(64, 8), 512, 0, stream>>>(Qf, Kf, Vt, Db, amask, skim, out);
}

// Round 4
// 196.194 us; speedup vs baseline: 1.1959x; 1.0549x over previous
//
#include <hip/hip_runtime.h>
#include <hip/hip_bf16.h>

// BertSelfAttention B=4,S=1024,HID=1024,H=16,D=64,MAXP=1024 — Round 11.
// R10 post-mortem: 8-wave r-split never raised resident waves (occ 19.8 vs
// 17.8) and was net slower than R7 (78.6 vs 71.4us). Kernel is latency-bound
// at ~2 waves/SIMD; occupancy can't be bought. R11 = R7 structure + ILP:
//  (1) Toeplitz ring re-indexed BY R (row l31 slot r&127) -> gather is one
//      aligned ds_read_b64 per (mt,g): 8 vector reads/iter vs 32 scalar u16.
//  (2) T-window production pipelined one iter ahead -> no intra-iteration
//      LDS write->read drain on the critical path (ring rows wave-private,
//      read-before-write program order).
//  (3) K/V/Db loads hoisted to iter top; VGPR headroom free at 2 blocks/CU
//      ((256,2): cap 256).
// ws: Xs[0,8M) Wt[8M,14M) Db[14M,14.25M) Qf[15M) Kf[23M) Vt[31M)

#define EPSV 1e-8f

typedef short bfrag __attribute__((ext_vector_type(8)));   // 8 bf16
typedef float cfrag __attribute__((ext_vector_type(16)));  // C/D 32x32
typedef int v2i __attribute__((ext_vector_type(2)));

__device__ __forceinline__ short f2bf(float f) {
    __hip_bfloat16 h = __float2bfloat16(f);
    return *reinterpret_cast<short*>(&h);
}
__device__ __forceinline__ float bf2f(short s) {
    unsigned int u = ((unsigned int)(unsigned short)s) << 16;
    return __builtin_bit_cast(float, u);
}
__device__ __forceinline__ unsigned int pk2(short a, short b) {
    return (unsigned int)(unsigned short)a | ((unsigned int)(unsigned short)b << 16);
}

// ---------------------------------------------------------------------------
// prep: fused cvt/swizzle. grid.x = 3648, 256 thr.
__global__ __launch_bounds__(256) void prep(
    const float* __restrict__ hidden, const float* __restrict__ Wq,
    const float* __restrict__ Wk, const float* __restrict__ Wv,
    const float* __restrict__ dist,
    short* __restrict__ Xs, short* __restrict__ Wt, short* __restrict__ Db)
{
    __shared__ short Tl[32 * 72];
    const int bid = blockIdx.x, tid = threadIdx.x;

    if (bid < 2048) {                      // X: 128 m-tiles x 16 k-groups
        const int mt = bid >> 4, kg = bid & 15;
        const int m_l = tid >> 3, k8 = (tid & 7) * 8;
        const float* src = hidden + (size_t)(mt * 32 + m_l) * 1024 + kg * 64 + k8;
        float4 v0 = *(const float4*)src, v1 = *(const float4*)(src + 4);
        short o[8];
        o[0] = f2bf(v0.x); o[1] = f2bf(v0.y); o[2] = f2bf(v0.z); o[3] = f2bf(v0.w);
        o[4] = f2bf(v1.x); o[5] = f2bf(v1.y); o[6] = f2bf(v1.z); o[7] = f2bf(v1.w);
        *(bfrag*)&Tl[m_l * 72 + k8] = *(bfrag*)o;
        __syncthreads();
        const int l31 = tid & 31, q2 = (tid >> 5) & 1, kc = tid >> 6;
        bfrag r = *(const bfrag*)&Tl[l31 * 72 + kc * 16 + q2 * 8];
        *(bfrag*)(Xs + ((size_t)(mt * 64 + kg * 4 + kc) * 64 + q2 * 32 + l31) * 8) = r;
    } else if (bid < 3584) {               // W: 3 z x 32 n-tiles x 16 k-groups
        const int t = bid - 2048, z = t >> 9, nt = (t >> 4) & 31, kg = t & 15;
        const float* W = (z == 0) ? Wq : ((z == 1) ? Wk : Wv);
        const int k_l = tid >> 2, n8 = (tid & 3) * 8;
        const float* src = W + (size_t)(kg * 64 + k_l) * 1024 + nt * 32 + n8;
        float4 v0 = *(const float4*)src, v1 = *(const float4*)(src + 4);
        float vv[8] = {v0.x, v0.y, v0.z, v0.w, v1.x, v1.y, v1.z, v1.w};
#pragma unroll
        for (int i = 0; i < 8; i++)
            Tl[(n8 + i) * 72 + k_l] = f2bf(vv[i]);   // transpose into LDS
        __syncthreads();
        const int l31 = tid & 31, q2 = (tid >> 5) & 1, kc = tid >> 6;
        bfrag r = *(const bfrag*)&Tl[l31 * 72 + kc * 16 + q2 * 8];
        *(bfrag*)(Wt + (size_t)z * 1048576
                  + ((size_t)(nt * 64 + kg * 4 + kc) * 64 + q2 * 32 + l31) * 8) = r;
    } else {                               // dist: 2047*64 = 131008 elems
        const int idx = (bid - 3584) * 256 + tid;
        if (idx < 16376) {
            const float* src = dist + (size_t)idx * 8;
            float4 v0 = *(const float4*)src, v1 = *(const float4*)(src + 4);
            short o[8];
            o[0] = f2bf(v0.x); o[1] = f2bf(v0.y); o[2] = f2bf(v0.z); o[3] = f2bf(v0.w);
            o[4] = f2bf(v1.x); o[5] = f2bf(v1.y); o[6] = f2bf(v1.z); o[7] = f2bf(v1.w);
            *(bfrag*)(Db + (size_t)idx * 8) = *(bfrag*)o;
        }
    }
}

// ---------------------------------------------------------------------------
// QKV GEMM, LDS-free. 128x128 block, 4 waves 2x2 of 64x64.
__global__ __launch_bounds__(256) void qkv_mfma(
    const short* __restrict__ Xs, const short* __restrict__ Wt,
    const float* __restrict__ bq, const float* __restrict__ bk,
    const float* __restrict__ bv,
    short* __restrict__ Qf, short* __restrict__ Kf, short* __restrict__ Vt)
{
    const int z = blockIdx.z;
    const short* W = Wt + (size_t)z * 1048576;
    const float* bias = (z == 0) ? bq : ((z == 1) ? bk : bv);
    // fold 1/sqrt(D) AND log2(e) into Q: 0.125 * 1.4426950408889634
    const float scale = (z == 0) ? 0.18033688011112042f : 1.0f;

    const int tid = threadIdx.x, lane = tid & 63, wid = tid >> 6;
    const int q2 = lane >> 5, l31 = lane & 31;
    const int wr = wid >> 1, wc = wid & 1;
    const int m0 = blockIdx.x * 128, n0 = blockIdx.y * 128;

    cfrag acc[2][2];
#pragma unroll
    for (int i = 0; i < 2; i++)
#pragma unroll
        for (int j = 0; j < 2; j++)
#pragma unroll
            for (int e = 0; e < 16; e++) acc[i][j][e] = 0.f;

    const short* ap0 = Xs + ((size_t)((m0 >> 5) + wr * 2 + 0) * 64 * 64 + lane) * 8;
    const short* ap1 = Xs + ((size_t)((m0 >> 5) + wr * 2 + 1) * 64 * 64 + lane) * 8;
    const short* bp0 = W  + ((size_t)((n0 >> 5) + wc * 2 + 0) * 64 * 64 + lane) * 8;
    const short* bp1 = W  + ((size_t)((n0 >> 5) + wc * 2 + 1) * 64 * 64 + lane) * 8;

#pragma unroll 4
    for (int kc = 0; kc < 64; kc++) {
        const int off = kc * 512;          // 64 chunks * 8 shorts
        bfrag a0 = *(const bfrag*)(ap0 + off);
        bfrag a1 = *(const bfrag*)(ap1 + off);
        bfrag b0 = *(const bfrag*)(bp0 + off);
        bfrag b1 = *(const bfrag*)(bp1 + off);
        acc[0][0] = __builtin_amdgcn_mfma_f32_32x32x16_bf16(a0, b0, acc[0][0], 0, 0, 0);
        acc[0][1] = __builtin_amdgcn_mfma_f32_32x32x16_bf16(a0, b1, acc[0][1], 0, 0, 0);
        acc[1][0] = __builtin_amdgcn_mfma_f32_32x32x16_bf16(a1, b0, acc[1][0], 0, 0, 0);
        acc[1][1] = __builtin_amdgcn_mfma_f32_32x32x16_bf16(a1, b1, acc[1][1], 0, 0, 0);
    }

    // epilogue: +bias, (Q: x scale), cvt bf16, scatter frag-major per bh
#pragma unroll
    for (int nt = 0; nt < 2; nt++) {
        const int c = n0 + wc * 64 + nt * 32 + l31;    // channel
        const float bval = bias[c];
        const int h = c >> 6;
        const int d = nt * 32 + l31;                   // c & 63
#pragma unroll
        for (int mt = 0; mt < 2; mt++) {
            const int tok0 = m0 + wr * 64 + mt * 32;
            const int bb = tok0 >> 10, s_base = tok0 & 1023;
            const size_t bhbase = (size_t)(bb * 16 + h) * 65536;
            if (z < 2) {
                short* outp = (z == 0) ? Qf : Kf;
                const size_t fbase = bhbase
                    + ((size_t)((s_base >> 5) * 4 + (d >> 4)) * 64
                       + ((d >> 3) & 1) * 32) * 8 + (d & 7);
#pragma unroll
                for (int reg = 0; reg < 16; reg++) {
                    const int row = (reg & 3) + 8 * (reg >> 2) + 4 * q2;
                    outp[fbase + (size_t)row * 8] = f2bf((acc[mt][nt][reg] + bval) * scale);
                }
            } else {
                // V^T frag-major: elem (d, s): ((d>>5)*64 + (s>>4))*64*8 ...
#pragma unroll
                for (int g = 0; g < 4; g++) {
                    const float e0 = acc[mt][nt][4 * g + 0] + bval;
                    const float e1 = acc[mt][nt][4 * g + 1] + bval;
                    const float e2 = acc[mt][nt][4 * g + 2] + bval;
                    const float e3 = acc[mt][nt][4 * g + 3] + bval;
                    uint2 w2;
                    w2.x = pk2(f2bf(e0), f2bf(e1));
                    w2.y = pk2(f2bf(e2), f2bf(e3));
                    const size_t flat = bhbase
                        + ((size_t)(nt * 64 + (s_base >> 4) + (g >> 1)) * 64
                           + (g & 1) * 32 + l31) * 8 + 4 * q2;
                    *(uint2*)(Vt + flat) = w2;
                }
            }
        }
    }
}

// ---------------------------------------------------------------------------
// Fused attention. grid (64 bh = x, 8 l-tiles = y), 256 thr (4 waves).
// Wave w owns l-cols [l0+32w, +32) for all r. Barrier-free main loop.
// Toeplitz ring indexed BY R: row l31 holds T(lg - r) at slot r&127.
// Production pipelined one iteration ahead (fills slots [r0+64, r0+127]).
__global__ __launch_bounds__(256, 2) void attn_mfma(
    const short* __restrict__ Qf, const short* __restrict__ Kf,
    const short* __restrict__ Vt, const short* __restrict__ Db,
    const float* __restrict__ amask, const int* __restrict__ skim,
    float* __restrict__ out)
{
    __shared__ short Tb[128 * 132];   // per-(wave,lane) r-ring, stride 132
    __shared__ float Lg[1024];        // g[r] = exp(amask)*skim

    const int tid = threadIdx.x, lane = tid & 63, w = tid >> 6;
    const int q2 = lane >> 5, l31 = lane & 31;
    const int bh = blockIdx.x, b = bh >> 4, hh = bh & 15;
    const int l0 = blockIdx.y * 128;

    {
        const int r4 = tid * 4;
        float4 am = *(const float4*)(amask + b * 1024 + r4);
        int4 sk = *(const int4*)(skim + b * 1024 + r4);
        Lg[r4 + 0] = __expf(am.x) * (float)sk.x;
        Lg[r4 + 1] = __expf(am.y) * (float)sk.y;
        Lg[r4 + 2] = __expf(am.z) * (float)sk.z;
        Lg[r4 + 3] = __expf(am.w) * (float)sk.w;
    }
    __syncthreads();

    const short* Qg = Qf + (size_t)bh * 65536;
    const short* Kg = Kf + (size_t)bh * 65536;
    const short* Vg = Vt + (size_t)bh * 65536;

    // Q B-frags (pre-scaled by log2e/8)
    bfrag qa[4];
#pragma unroll
    for (int c = 0; c < 4; c++)
        qa[c] = *(const bfrag*)(Qg + ((size_t)(((l0 >> 5) + w) * 4 + c) * 64 + lane) * 8);

    cfrag oacc[2];
#pragma unroll
    for (int mt = 0; mt < 2; mt++)
#pragma unroll
        for (int e = 0; e < 16; e++) oacc[mt][e] = 0.f;
    float es[4] = {0.f, 0.f, 0.f, 0.f};

    const int Lband = l0 + 32 * w;          // wave's first l-column
    const int lg = Lband + l31;             // this lane's l-column
    const int rowb = (32 * w + l31) * 132;  // private ring row (shorts)

    for (int r0 = -128; r0 < 1024; r0 += 64) {
        const bool produce = r0 < 960;

        // ---- issue production's Db loads early (independent) ----
        bfrag pb[2][4];
        if (produce) {
#pragma unroll
            for (int mt = 0; mt < 2; mt++) {
                const int D0 = Lband - r0 - 128 + 32 * mt;   // dist block base
                const int er = min(max(D0 + l31 + 1023, 0), 2046);
#pragma unroll
                for (int kc = 0; kc < 4; kc++)
                    pb[mt][kc] = *(const bfrag*)(Db + (size_t)er * 64 + kc * 16 + q2 * 8);
            }
        }

        if (r0 >= 0) {
            // ---- K and V frag loads, hoisted ----
            bfrag kb[2][4], vbl[4][2];
#pragma unroll
            for (int mt = 0; mt < 2; mt++)
#pragma unroll
                for (int kc = 0; kc < 4; kc++)
                    kb[mt][kc] = *(const bfrag*)(Kg
                        + ((size_t)(((r0 >> 5) + mt) * 4 + kc) * 64 + lane) * 8);
#pragma unroll
            for (int kc = 0; kc < 4; kc++)
#pragma unroll
                for (int mtd = 0; mtd < 2; mtd++)
                    vbl[kc][mtd] = *(const bfrag*)(Vg
                        + ((size_t)(mtd * 64 + (r0 >> 4) + kc) * 64 + lane) * 8);

            // ---- per 32-r block: scores, softmax numerators, relayout, PV ----
#pragma unroll
            for (int mt = 0; mt < 2; mt++) {
                cfrag sfr;
#pragma unroll
                for (int e = 0; e < 16; e++) sfr[e] = 0.f;
#pragma unroll
                for (int kc = 0; kc < 4; kc++)
                    sfr = __builtin_amdgcn_mfma_f32_32x32x16_bf16(
                        kb[mt][kc], qa[kc], sfr, 0, 0, 0);

                unsigned int P[4][2];
#pragma unroll
                for (int g = 0; g < 4; g++) {
                    const int rb = r0 + 32 * mt + 8 * g + 4 * q2;
                    float4 g4 = *(const float4*)&Lg[rb];
                    // one aligned b64: T(lg-r) for r = rb..rb+3 (ring by r)
                    v2i tr = *(const v2i*)&Tb[rowb + (rb & 127)];
                    const float tv0 = __builtin_bit_cast(float, (unsigned)tr[0] << 16);
                    const float tv1 = __builtin_bit_cast(float, (unsigned)tr[0] & 0xffff0000u);
                    const float tv2 = __builtin_bit_cast(float, (unsigned)tr[1] << 16);
                    const float tv3 = __builtin_bit_cast(float, (unsigned)tr[1] & 0xffff0000u);
                    float ev0 = __builtin_amdgcn_exp2f(sfr[4 * g + 0] + tv0) * g4.x;
                    float ev1 = __builtin_amdgcn_exp2f(sfr[4 * g + 1] + tv1) * g4.y;
                    float ev2 = __builtin_amdgcn_exp2f(sfr[4 * g + 2] + tv2) * g4.z;
                    float ev3 = __builtin_amdgcn_exp2f(sfr[4 * g + 3] + tv3) * g4.w;
                    es[0] += ev0; es[1] += ev1; es[2] += ev2; es[3] += ev3;
                    P[g][0] = pk2(f2bf(ev0), f2bf(ev1));
                    P[g][1] = pk2(f2bf(ev2), f2bf(ev3));
                }
                // in-register relayout: score C-frag -> PV B-frag
#pragma unroll
                for (int c = 0; c < 2; c++) {
                    v2i s0 = __builtin_amdgcn_permlane32_swap(
                        (int)P[2 * c][0], (int)P[2 * c + 1][0], false, false);
                    v2i s1 = __builtin_amdgcn_permlane32_swap(
                        (int)P[2 * c][1], (int)P[2 * c + 1][1], false, false);
                    union { bfrag f; int d[4]; } u;
                    u.d[0] = s0[0]; u.d[1] = s1[0]; u.d[2] = s0[1]; u.d[3] = s1[1];
                    const int kc = 2 * mt + c;
#pragma unroll
                    for (int mtd = 0; mtd < 2; mtd++)
                        oacc[mtd] = __builtin_amdgcn_mfma_f32_32x32x16_bf16(
                            vbl[kc][mtd], u.f, oacc[mtd], 0, 0, 0);
                }
            }
        }

        // ---- production: T window for [r0+64, r0+127] (after gathers) ----
        if (produce) {
#pragma unroll
            for (int mt = 0; mt < 2; mt++) {
                cfrag t;
#pragma unroll
                for (int e = 0; e < 16; e++) t[e] = 0.f;
#pragma unroll
                for (int kc = 0; kc < 4; kc++)
                    t = __builtin_amdgcn_mfma_f32_32x32x16_bf16(
                        pb[mt][kc], qa[kc], t, 0, 0, 0);
#pragma unroll
                for (int e = 0; e < 16; e++) {
                    const int rr = (e & 3) + 8 * (e >> 2) + 4 * q2;
                    Tb[rowb + ((l31 + r0 - 32 * mt - rr) & 127)] = f2bf(t[e]);
                }
            }
        }
    }

    // ---- finalize ----
    float esum = (es[0] + es[1]) + (es[2] + es[3]);
    const float den = EPSV + esum + __shfl_xor(esum, 32);
    const float inv = 1.0f / den;
    float* ob = out + ((size_t)(b * 1024 + lg) * 1024) + hh * 64;
#pragma unroll
    for (int mtd = 0; mtd < 2; mtd++) {
#pragma unroll
        for (int g = 0; g < 4; g++) {
            float4 o;
            o.x = oacc[mtd][4 * g + 0] * inv;
            o.y = oacc[mtd][4 * g + 1] * inv;
            o.z = oacc[mtd][4 * g + 2] * inv;
            o.w = oacc[mtd][4 * g + 3] * inv;
            *(float4*)(ob + 32 * mtd + 8 * g + 4 * q2) = o;
        }
    }
}

// ---------------------------------------------------------------------------
extern "C" void kernel_launch(void* const* d_in, const int* in_sizes, int n_in,
                              void* d_out, int out_size, void* d_ws, size_t ws_size,
                              hipStream_t stream) {
    const float* hidden = (const float*)d_in[0];
    const float* amask  = (const float*)d_in[1];
    const int*   skim   = (const int*)d_in[2];
    const float* Wq     = (const float*)d_in[3];
    const float* bq     = (const float*)d_in[4];
    const float* Wk     = (const float*)d_in[5];
    const float* bk     = (const float*)d_in[6];
    const float* Wv     = (const float*)d_in[7];
    const float* bv     = (const float*)d_in[8];
    const float* dist   = (const float*)d_in[9];
    float* out = (float*)d_out;

    char* w = (char*)d_ws;
    short* Xs  = (short*)(w);                        // 8 MB frag-major X
    short* Wt  = (short*)(w + ((size_t)8 << 20));    // 6 MB frag-major W^T
    short* Db  = (short*)(w + ((size_t)14 << 20));   // 0.25 MB dist bf16
    short* Qf  = (short*)(w + ((size_t)15 << 20));   // 8 MB frag-major Q
    short* Kf  = (short*)(w + ((size_t)23 << 20));   // 8 MB frag-major K
    short* Vt  = (short*)(w + ((size_t)31 << 20));   // 8 MB frag-major V^T

    prep<<<3648, 256, 0, stream>>>(hidden, Wq, Wk, Wv, dist, Xs, Wt, Db);
    qkv_mfma<<<dim3(32, 8, 3), 256, 0, stream>>>(Xs, Wt, bq, bk, bv, Qf, Kf, Vt);
    attn_mfma<<<dim3(64, 8), 256, 0, stream>>>(Qf, Kf, Vt, Db, amask, skim, out);
}